// Round 1
// baseline (165.924 us; speedup 1.0000x reference)
//
#include <hip/hip_runtime.h>
#include <hip/hip_bf16.h>

#define B_ 2
#define N_ 512
#define DS_ 384
#define DP_ 128
#define H_ 16
#define DH_ 64
#define DI_ 1024
#define MAXSEQ 2048
#define PAD 8

typedef float f32x4 __attribute__((ext_vector_type(4)));
typedef short bf16x8 __attribute__((ext_vector_type(8)));

__device__ __forceinline__ unsigned short f2b(float f) {
    unsigned int u = __builtin_bit_cast(unsigned int, f);
    u += 0x7FFFu + ((u >> 16) & 1u);
    return (unsigned short)(u >> 16);
}
__device__ __forceinline__ float b2f(unsigned short s) {
    unsigned int u = ((unsigned int)s) << 16;
    return __builtin_bit_cast(float, u);
}

// ---------------- weight transpose: f32 (R,C) -> bf16 (C,R) ----------------
__global__ __launch_bounds__(256) void k_transpose(const float* __restrict__ in,
                                                   unsigned short* __restrict__ out,
                                                   int R, int C) {
    __shared__ float tile[32][33];
    int c0 = blockIdx.x * 32, r0 = blockIdx.y * 32;
    int tx = threadIdx.x & 31, ty = threadIdx.x >> 5;
    #pragma unroll
    for (int i = ty; i < 32; i += 8)
        tile[i][tx] = in[(long)(r0 + i) * C + (c0 + tx)];
    __syncthreads();
    #pragma unroll
    for (int i = ty; i < 32; i += 8)
        out[(long)(c0 + i) * R + (r0 + tx)] = f2b(tile[tx][i]);
}

// ---------------- bias: LN(pairwise) @ w_bias + abb -> bf16 [b][h][i][j] ----
__global__ __launch_bounds__(256) void k_bias(const float* __restrict__ pw,
                                              const float* __restrict__ gamma,
                                              const float* __restrict__ beta,
                                              const float* __restrict__ wb,
                                              const float* __restrict__ abb,
                                              unsigned short* __restrict__ biasP) {
    __shared__ float Gt[DP_][H_];
    __shared__ float Ssum[H_], Tsum[H_];
    int t = threadIdx.x;
    for (int idx = t; idx < DP_ * H_; idx += 256)
        Gt[idx >> 4][idx & 15] = gamma[idx >> 4] * wb[idx];
    if (t < 32) {
        int h = t & 15;
        const float* src = (t >= 16) ? beta : gamma;
        float s = 0.f;
        for (int d = 0; d < DP_; ++d) s = fmaf(src[d], wb[d * H_ + h], s);
        if (t >= 16) Tsum[h] = s; else Ssum[h] = s;
    }
    __syncthreads();
    long p = (long)blockIdx.x * 256 + t;            // position index, < B*N*N
    int j = (int)(p & (N_ - 1));
    int i = (int)((p >> 9) & (N_ - 1));
    long b = p >> 18;
    const float4* x4 = (const float4*)(pw + p * DP_);
    float sum = 0.f, sumsq = 0.f;
    float dot[H_];
    #pragma unroll
    for (int h = 0; h < H_; ++h) dot[h] = 0.f;
    #pragma unroll 4
    for (int k = 0; k < DP_ / 4; ++k) {
        float4 x = x4[k];
        #pragma unroll
        for (int c = 0; c < 4; ++c) {
            float xv = (c == 0) ? x.x : (c == 1) ? x.y : (c == 2) ? x.z : x.w;
            int d = k * 4 + c;
            sum += xv;
            sumsq = fmaf(xv, xv, sumsq);
            #pragma unroll
            for (int hq = 0; hq < 4; ++hq) {
                float4 g = *(const float4*)&Gt[d][hq * 4];
                dot[hq * 4 + 0] = fmaf(xv, g.x, dot[hq * 4 + 0]);
                dot[hq * 4 + 1] = fmaf(xv, g.y, dot[hq * 4 + 1]);
                dot[hq * 4 + 2] = fmaf(xv, g.z, dot[hq * 4 + 2]);
                dot[hq * 4 + 3] = fmaf(xv, g.w, dot[hq * 4 + 3]);
            }
        }
    }
    float mu = sum * (1.f / DP_);
    float var = fmaf(sumsq, 1.f / DP_, -mu * mu);
    float rstd = rsqrtf(var + 1e-5f);
    float ab = abb[(long)i * MAXSEQ + j];
    unsigned short* outp = biasP + ((b * H_) * N_ + i) * N_ + j;
    #pragma unroll
    for (int h = 0; h < H_; ++h) {
        float v = fmaf(rstd, dot[h] - mu * Ssum[h], Tsum[h] + ab);
        outp[(long)h * N_ * N_] = f2b(v);
    }
}

// ---------------- QKVG projection GEMM (M=1024, N=4096, K=384) --------------
__global__ __launch_bounds__(256) void k_proj(const float* __restrict__ X,
                                              const unsigned short* __restrict__ Wt,
                                              unsigned short* __restrict__ Qb,
                                              unsigned short* __restrict__ Kb,
                                              unsigned short* __restrict__ Vt,
                                              unsigned short* __restrict__ Xg) {
    __shared__ unsigned short As[128][64 + PAD];
    __shared__ unsigned short Bs[128][64 + PAD];
    int m0 = blockIdx.x * 128;
    int n0 = blockIdx.y * 128;
    int t = threadIdx.x;
    int wave = t >> 6, lane = t & 63;
    int wr = wave >> 1, wc = wave & 1;
    int lane15 = lane & 15, kg = lane >> 4;
    f32x4 acc[4][4] = {};
    for (int k0 = 0; k0 < DS_; k0 += 64) {
        __syncthreads();
        {
            int r = t >> 1, half = t & 1;
            const float4* src = (const float4*)(X + (long)(m0 + r) * DS_ + k0 + half * 32);
            unsigned short* dst = &As[r][half * 32];
            #pragma unroll
            for (int ii = 0; ii < 8; ++ii) {
                float4 v = src[ii];
                dst[ii * 4 + 0] = f2b(v.x); dst[ii * 4 + 1] = f2b(v.y);
                dst[ii * 4 + 2] = f2b(v.z); dst[ii * 4 + 3] = f2b(v.w);
            }
            const uint4* wsrc = (const uint4*)(Wt + (long)(n0 + r) * DS_ + k0 + half * 32);
            uint4* wdst = (uint4*)&Bs[r][half * 32];
            wdst[0] = wsrc[0]; wdst[1] = wsrc[1]; wdst[2] = wsrc[2]; wdst[3] = wsrc[3];
        }
        __syncthreads();
        #pragma unroll
        for (int ks = 0; ks < 2; ++ks) {
            bf16x8 a[4], bb[4];
            #pragma unroll
            for (int mf = 0; mf < 4; ++mf)
                a[mf] = *(const bf16x8*)&As[wr * 64 + mf * 16 + lane15][ks * 32 + kg * 8];
            #pragma unroll
            for (int nf = 0; nf < 4; ++nf)
                bb[nf] = *(const bf16x8*)&Bs[wc * 64 + nf * 16 + lane15][ks * 32 + kg * 8];
            #pragma unroll
            for (int mf = 0; mf < 4; ++mf)
                #pragma unroll
                for (int nf = 0; nf < 4; ++nf)
                    acc[mf][nf] = __builtin_amdgcn_mfma_f32_16x16x32_bf16(a[mf], bb[nf], acc[mf][nf], 0, 0, 0);
        }
    }
    int p = n0 >> 10;                 // which projection (q,k,v,g)
    int lgrp = lane >> 4;
    #pragma unroll
    for (int mf = 0; mf < 4; ++mf) {
        #pragma unroll
        for (int nf = 0; nf < 4; ++nf) {
            int col = n0 + wc * 64 + nf * 16 + lane15;
            int ch = col & 1023;
            int h = ch >> 6, dh = ch & 63;
            int row0 = m0 + wr * 64 + mf * 16 + lgrp * 4;
            if (p == 0 || p == 1) {
                unsigned short* base = (p == 0) ? Qb : Kb;
                #pragma unroll
                for (int r = 0; r < 4; ++r) {
                    int row = row0 + r;
                    int b = row >> 9, n = row & 511;
                    base[(((long)(b * 16 + h)) * 512 + n) * 64 + dh] = f2b(acc[mf][nf][r]);
                }
            } else if (p == 2) {
                int b = row0 >> 9, n = row0 & 511;
                ushort4 v;
                v.x = f2b(acc[mf][nf][0]); v.y = f2b(acc[mf][nf][1]);
                v.z = f2b(acc[mf][nf][2]); v.w = f2b(acc[mf][nf][3]);
                *(ushort4*)&Vt[(((long)(b * 16 + h)) * 64 + dh) * 512 + n] = v;
            } else {
                #pragma unroll
                for (int r = 0; r < 4; ++r) {
                    int row = row0 + r;
                    Xg[(long)row * 1024 + ch] = f2b(acc[mf][nf][r]);
                }
            }
        }
    }
}

// ---------------- scores: S = 0.125*Q@K^T + bias (in-place, bf16) -----------
__global__ __launch_bounds__(256) void k_scores(const unsigned short* __restrict__ Qb,
                                                const unsigned short* __restrict__ Kb,
                                                unsigned short* __restrict__ SP) {
    __shared__ unsigned short As[128][64 + PAD];
    __shared__ unsigned short Bs[128][64 + PAD];
    int bh = blockIdx.y;
    int i0 = (blockIdx.x & 3) * 128;
    int j0 = (blockIdx.x >> 2) * 128;
    const unsigned short* Q = Qb + (long)bh * 512 * 64;
    const unsigned short* K = Kb + (long)bh * 512 * 64;
    unsigned short* S = SP + (long)bh * 512 * 512;
    int t = threadIdx.x, wave = t >> 6, lane = t & 63;
    int wr = wave >> 1, wc = wave & 1;
    int lane15 = lane & 15, kg = lane >> 4;
    {
        int r = t >> 1, half = t & 1;
        const uint4* qsrc = (const uint4*)(Q + (long)(i0 + r) * 64 + half * 32);
        uint4* qdst = (uint4*)&As[r][half * 32];
        qdst[0] = qsrc[0]; qdst[1] = qsrc[1]; qdst[2] = qsrc[2]; qdst[3] = qsrc[3];
        const uint4* ksrc = (const uint4*)(K + (long)(j0 + r) * 64 + half * 32);
        uint4* kdst = (uint4*)&Bs[r][half * 32];
        kdst[0] = ksrc[0]; kdst[1] = ksrc[1]; kdst[2] = ksrc[2]; kdst[3] = ksrc[3];
    }
    __syncthreads();
    f32x4 acc[4][4] = {};
    #pragma unroll
    for (int ks = 0; ks < 2; ++ks) {
        bf16x8 a[4], bb[4];
        #pragma unroll
        for (int mf = 0; mf < 4; ++mf)
            a[mf] = *(const bf16x8*)&As[wr * 64 + mf * 16 + lane15][ks * 32 + kg * 8];
        #pragma unroll
        for (int nf = 0; nf < 4; ++nf)
            bb[nf] = *(const bf16x8*)&Bs[wc * 64 + nf * 16 + lane15][ks * 32 + kg * 8];
        #pragma unroll
        for (int mf = 0; mf < 4; ++mf)
            #pragma unroll
            for (int nf = 0; nf < 4; ++nf)
                acc[mf][nf] = __builtin_amdgcn_mfma_f32_16x16x32_bf16(a[mf], bb[nf], acc[mf][nf], 0, 0, 0);
    }
    int lgrp = lane >> 4;
    #pragma unroll
    for (int mf = 0; mf < 4; ++mf) {
        #pragma unroll
        for (int nf = 0; nf < 4; ++nf) {
            int jcol = j0 + wc * 64 + nf * 16 + lane15;
            int irow0 = i0 + wr * 64 + mf * 16 + lgrp * 4;
            #pragma unroll
            for (int r = 0; r < 4; ++r) {
                long addr = (long)(irow0 + r) * 512 + jcol;
                float bias = b2f(S[addr]);
                S[addr] = f2b(fmaf(acc[mf][nf][r], 0.125f, bias));
            }
        }
    }
}

// ---------------- softmax over rows of S (wave per row) ---------------------
__global__ __launch_bounds__(256) void k_softmax(unsigned short* __restrict__ SP) {
    int wave = threadIdx.x >> 6, lane = threadIdx.x & 63;
    long row = (long)blockIdx.x * 4 + wave;
    unsigned short* Srow = SP + row * 512;
    uint4 raw = *(const uint4*)&Srow[lane * 8];
    unsigned short* rs = (unsigned short*)&raw;
    float v[8];
    #pragma unroll
    for (int e = 0; e < 8; ++e) v[e] = b2f(rs[e]);
    float m = v[0];
    #pragma unroll
    for (int e = 1; e < 8; ++e) m = fmaxf(m, v[e]);
    #pragma unroll
    for (int off = 1; off < 64; off <<= 1) m = fmaxf(m, __shfl_xor(m, off));
    float s = 0.f;
    #pragma unroll
    for (int e = 0; e < 8; ++e) { v[e] = __expf(v[e] - m); s += v[e]; }
    #pragma unroll
    for (int off = 1; off < 64; off <<= 1) s += __shfl_xor(s, off);
    float inv = 1.f / s;
    #pragma unroll
    for (int e = 0; e < 8; ++e) rs[e] = f2b(v[e] * inv);
    *(uint4*)&Srow[lane * 8] = raw;
}

// ---------------- PV + sigmoid gating: Og = (P@V) * sigmoid(Xg) -------------
__global__ __launch_bounds__(256) void k_pv(const unsigned short* __restrict__ SP,
                                            const unsigned short* __restrict__ Vt,
                                            const unsigned short* __restrict__ Xg,
                                            unsigned short* __restrict__ Og) {
    __shared__ unsigned short Ps[64][64 + PAD];
    __shared__ unsigned short Vs[64][64 + PAD];
    int bh = blockIdx.y;
    int b = bh >> 4, h = bh & 15;
    int i0 = blockIdx.x * 64;
    const unsigned short* P = SP + (long)bh * 512 * 512;
    const unsigned short* V = Vt + (long)bh * 64 * 512;
    int t = threadIdx.x, wave = t >> 6, lane = t & 63;
    int lane15 = lane & 15, kg = lane >> 4;
    f32x4 acc[4] = {};
    for (int k0 = 0; k0 < 512; k0 += 64) {
        __syncthreads();
        {
            int r = t >> 2, q = t & 3;
            const uint4* src = (const uint4*)(P + (long)(i0 + r) * 512 + k0 + q * 16);
            uint4* dst = (uint4*)&Ps[r][q * 16];
            dst[0] = src[0]; dst[1] = src[1];
            const uint4* vsrc = (const uint4*)(V + (long)r * 512 + k0 + q * 16);
            uint4* vdst = (uint4*)&Vs[r][q * 16];
            vdst[0] = vsrc[0]; vdst[1] = vsrc[1];
        }
        __syncthreads();
        #pragma unroll
        for (int ks = 0; ks < 2; ++ks) {
            bf16x8 a = *(const bf16x8*)&Ps[wave * 16 + lane15][ks * 32 + kg * 8];
            #pragma unroll
            for (int nf = 0; nf < 4; ++nf) {
                bf16x8 bfr = *(const bf16x8*)&Vs[nf * 16 + lane15][ks * 32 + kg * 8];
                acc[nf] = __builtin_amdgcn_mfma_f32_16x16x32_bf16(a, bfr, acc[nf], 0, 0, 0);
            }
        }
    }
    int lgrp = lane >> 4;
    #pragma unroll
    for (int nf = 0; nf < 4; ++nf) {
        int dh = nf * 16 + lane15;
        #pragma unroll
        for (int r = 0; r < 4; ++r) {
            int i = i0 + wave * 16 + lgrp * 4 + r;
            long grow = (long)b * 512 + i;
            float xgv = b2f(Xg[grow * 1024 + h * 64 + dh]);
            float gate = 1.f / (1.f + __expf(-xgv));
            Og[grow * 1024 + h * 64 + dh] = f2b(acc[nf][r] * gate);
        }
    }
}

// ---------------- output GEMM: out = Og @ w_o (M=1024,N=384,K=1024) ---------
__global__ __launch_bounds__(256) void k_out(const unsigned short* __restrict__ Og,
                                             const unsigned short* __restrict__ Wot,
                                             float* __restrict__ out) {
    __shared__ unsigned short As[128][64 + PAD];
    __shared__ unsigned short Bs[128][64 + PAD];
    int m0 = blockIdx.x * 128, n0 = blockIdx.y * 128;
    int t = threadIdx.x, wave = t >> 6, lane = t & 63;
    int wr = wave >> 1, wc = wave & 1;
    int lane15 = lane & 15, kg = lane >> 4;
    f32x4 acc[4][4] = {};
    for (int k0 = 0; k0 < 1024; k0 += 64) {
        __syncthreads();
        {
            int r = t >> 1, half = t & 1;
            const uint4* src = (const uint4*)(Og + (long)(m0 + r) * 1024 + k0 + half * 32);
            uint4* dst = (uint4*)&As[r][half * 32];
            dst[0] = src[0]; dst[1] = src[1]; dst[2] = src[2]; dst[3] = src[3];
            const uint4* wsrc = (const uint4*)(Wot + (long)(n0 + r) * 1024 + k0 + half * 32);
            uint4* wdst = (uint4*)&Bs[r][half * 32];
            wdst[0] = wsrc[0]; wdst[1] = wsrc[1]; wdst[2] = wsrc[2]; wdst[3] = wsrc[3];
        }
        __syncthreads();
        #pragma unroll
        for (int ks = 0; ks < 2; ++ks) {
            bf16x8 a[4], bb[4];
            #pragma unroll
            for (int mf = 0; mf < 4; ++mf)
                a[mf] = *(const bf16x8*)&As[wr * 64 + mf * 16 + lane15][ks * 32 + kg * 8];
            #pragma unroll
            for (int nf = 0; nf < 4; ++nf)
                bb[nf] = *(const bf16x8*)&Bs[wc * 64 + nf * 16 + lane15][ks * 32 + kg * 8];
            #pragma unroll
            for (int mf = 0; mf < 4; ++mf)
                #pragma unroll
                for (int nf = 0; nf < 4; ++nf)
                    acc[mf][nf] = __builtin_amdgcn_mfma_f32_16x16x32_bf16(a[mf], bb[nf], acc[mf][nf], 0, 0, 0);
        }
    }
    int lgrp = lane >> 4;
    #pragma unroll
    for (int mf = 0; mf < 4; ++mf) {
        #pragma unroll
        for (int nf = 0; nf < 4; ++nf) {
            int col = n0 + wc * 64 + nf * 16 + lane15;
            int row0 = m0 + wr * 64 + mf * 16 + lgrp * 4;
            #pragma unroll
            for (int r = 0; r < 4; ++r)
                out[(long)(row0 + r) * DS_ + col] = acc[mf][nf][r];
        }
    }
}

extern "C" void kernel_launch(void* const* d_in, const int* in_sizes, int n_in,
                              void* d_out, int out_size, void* d_ws, size_t ws_size,
                              hipStream_t stream) {
    const float* single = (const float*)d_in[0];
    const float* pw     = (const float*)d_in[1];
    const float* gamma  = (const float*)d_in[2];
    const float* beta   = (const float*)d_in[3];
    const float* wb     = (const float*)d_in[4];
    const float* abb    = (const float*)d_in[5];
    const float* wq     = (const float*)d_in[6];
    const float* wk     = (const float*)d_in[7];
    const float* wv     = (const float*)d_in[8];
    const float* wg     = (const float*)d_in[9];
    const float* wo     = (const float*)d_in[10];
    float* out = (float*)d_out;
    char* ws = (char*)d_ws;

    unsigned short* SP  = (unsigned short*)(ws);                 // 16 MB: bias -> scores -> probs
    unsigned short* Qb  = (unsigned short*)(ws + 16777216);      // 2 MB
    unsigned short* Kb  = (unsigned short*)(ws + 18874368);      // 2 MB
    unsigned short* Vt  = (unsigned short*)(ws + 20971520);      // 2 MB  [b][h][dh][n]
    unsigned short* Xg  = (unsigned short*)(ws + 23068672);      // 2 MB
    unsigned short* Og  = (unsigned short*)(ws + 25165824);      // 2 MB
    unsigned short* Wt  = (unsigned short*)(ws + 27262976);      // 3 MB  [4*1024][384]
    unsigned short* Wot = (unsigned short*)(ws + 30408704);      // 0.75 MB [384][1024]

    k_transpose<<<dim3(32, 12), 256, 0, stream>>>(wq, Wt + 0L * 1024 * 384, 384, 1024);
    k_transpose<<<dim3(32, 12), 256, 0, stream>>>(wk, Wt + 1L * 1024 * 384, 384, 1024);
    k_transpose<<<dim3(32, 12), 256, 0, stream>>>(wv, Wt + 2L * 1024 * 384, 384, 1024);
    k_transpose<<<dim3(32, 12), 256, 0, stream>>>(wg, Wt + 3L * 1024 * 384, 384, 1024);
    k_transpose<<<dim3(12, 32), 256, 0, stream>>>(wo, Wot, 1024, 384);

    k_bias<<<2048, 256, 0, stream>>>(pw, gamma, beta, wb, abb, SP);
    k_proj<<<dim3(8, 32), 256, 0, stream>>>(single, Wt, Qb, Kb, Vt, Xg);
    k_scores<<<dim3(16, 32), 256, 0, stream>>>(Qb, Kb, SP);
    k_softmax<<<4096, 256, 0, stream>>>(SP);
    k_pv<<<dim3(8, 32), 256, 0, stream>>>(SP, Vt, Xg, Og);
    k_out<<<dim3(8, 3), 256, 0, stream>>>(Og, Wot, out);
}

// Round 4
// 145.944 us; speedup vs baseline: 1.1369x; 1.1369x over previous
//
#include <hip/hip_runtime.h>
#include <hip/hip_bf16.h>

#define B_ 2
#define N_ 512
#define DS_ 384
#define DP_ 128
#define H_ 16
#define DH_ 64
#define DI_ 1024
#define MAXSEQ 2048
#define PAD 8

typedef float f32x4 __attribute__((ext_vector_type(4)));
typedef short bf16x8 __attribute__((ext_vector_type(8)));

__device__ __forceinline__ unsigned short f2b(float f) {
    unsigned int u = __builtin_bit_cast(unsigned int, f);
    u += 0x7FFFu + ((u >> 16) & 1u);
    return (unsigned short)(u >> 16);
}
__device__ __forceinline__ float b2f(unsigned short s) {
    unsigned int u = ((unsigned int)s) << 16;
    return __builtin_bit_cast(float, u);
}

// ---------------- all weight transposes in one launch ----------------------
__global__ __launch_bounds__(256) void k_transpose_all(const float* __restrict__ wq,
                                                       const float* __restrict__ wk,
                                                       const float* __restrict__ wv,
                                                       const float* __restrict__ wg,
                                                       const float* __restrict__ wo,
                                                       unsigned short* __restrict__ Wt,
                                                       unsigned short* __restrict__ Wot) {
    __shared__ float tile[32][33];
    int z = blockIdx.z;
    const float* in;
    unsigned short* out;
    int R, C;
    if (z < 4) {
        in = (z == 0) ? wq : (z == 1) ? wk : (z == 2) ? wv : wg;
        out = Wt + (long)z * 1024 * 384;
        R = 384; C = 1024;
    } else {
        in = wo; out = Wot; R = 1024; C = 384;
    }
    int c0 = blockIdx.x * 32, r0 = blockIdx.y * 32;
    if (c0 >= C || r0 >= R) return;
    int tx = threadIdx.x & 31, ty = threadIdx.x >> 5;
    #pragma unroll
    for (int i = ty; i < 32; i += 8)
        tile[i][tx] = in[(long)(r0 + i) * C + (c0 + tx)];
    __syncthreads();
    #pragma unroll
    for (int i = ty; i < 32; i += 8)
        out[(long)(c0 + i) * R + (r0 + tx)] = f2b(tile[tx][i]);
}

// ---------------- bias: LN(pairwise) @ w_bias + abb -> bf16 [b][h][i][j] ----
// v2: LDS-staged coalesced reads (128B segments), thread-per-row compute.
__global__ __launch_bounds__(256) void k_bias(const float* __restrict__ pw,
                                              const float* __restrict__ gamma,
                                              const float* __restrict__ beta,
                                              const float* __restrict__ wb,
                                              const float* __restrict__ abb,
                                              unsigned short* __restrict__ biasP) {
    __shared__ float Gt[DP_][H_];        // 8 KB  gamma[d]*wb[d][h]
    __shared__ float Ssum[H_], Tsum[H_];
    __shared__ float Xs[256][33];        // 33.8 KB, +1 pad -> conflict-free row reads
    int t = threadIdx.x;
    for (int idx = t; idx < DP_ * H_; idx += 256)
        Gt[idx >> 4][idx & 15] = gamma[idx >> 4] * wb[idx];
    if (t < 32) {
        int h = t & 15;
        const float* src = (t >= 16) ? beta : gamma;
        float s = 0.f;
        for (int d = 0; d < DP_; ++d) s = fmaf(src[d], wb[d * H_ + h], s);
        if (t >= 16) Tsum[h] = s; else Ssum[h] = s;
    }
    __syncthreads();
    long p0 = (long)blockIdx.x * 256;     // first row of this block's tile
    float sum = 0.f, sumsq = 0.f;
    float dot[H_];
    #pragma unroll
    for (int h = 0; h < H_; ++h) dot[h] = 0.f;

    for (int kc = 0; kc < 4; ++kc) {      // 4 chunks of 32 features
        if (kc) __syncthreads();          // all readers of Xs done
        #pragma unroll
        for (int i = 0; i < 8; ++i) {
            int f = i * 256 + t;
            int R = f >> 3, c = f & 7;    // 8 lanes per row -> 128B contiguous per row
            float4 v = *(const float4*)(pw + ((p0 + R) << 7) + kc * 32 + c * 4);
            float* xp = &Xs[0][0] + R * 33 + c * 4;
            xp[0] = v.x; xp[1] = v.y; xp[2] = v.z; xp[3] = v.w;
        }
        __syncthreads();
        const float* xr = &Xs[0][0] + t * 33;   // bank = (t + k) % 32 -> conflict-free
        #pragma unroll 8
        for (int k = 0; k < 32; ++k) {
            float xv = xr[k];
            int d = kc * 32 + k;
            sum += xv;
            sumsq = fmaf(xv, xv, sumsq);
            #pragma unroll
            for (int hq = 0; hq < 4; ++hq) {
                float4 g = *(const float4*)&Gt[d][hq * 4];   // uniform broadcast
                dot[hq * 4 + 0] = fmaf(xv, g.x, dot[hq * 4 + 0]);
                dot[hq * 4 + 1] = fmaf(xv, g.y, dot[hq * 4 + 1]);
                dot[hq * 4 + 2] = fmaf(xv, g.z, dot[hq * 4 + 2]);
                dot[hq * 4 + 3] = fmaf(xv, g.w, dot[hq * 4 + 3]);
            }
        }
    }
    long p = p0 + t;
    int j = (int)(p & (N_ - 1));
    int i = (int)((p >> 9) & (N_ - 1));
    long b = p >> 18;
    float mu = sum * (1.f / DP_);
    float var = fmaf(sumsq, 1.f / DP_, -mu * mu);
    float rstd = rsqrtf(var + 1e-5f);
    float ab = abb[(long)i * MAXSEQ + j];
    unsigned short* outp = biasP + ((b * H_) * N_ + i) * N_ + j;
    #pragma unroll
    for (int h = 0; h < H_; ++h) {
        float v = fmaf(rstd, dot[h] - mu * Ssum[h], Tsum[h] + ab);
        outp[(long)h * N_ * N_] = f2b(v);
    }
}

// ---------------- QKVG projection GEMM (M=1024, N=4096, K=384) --------------
// Q is pre-scaled by 0.125 (folded attention scale).
__global__ __launch_bounds__(256) void k_proj(const float* __restrict__ X,
                                              const unsigned short* __restrict__ Wt,
                                              unsigned short* __restrict__ Qb,
                                              unsigned short* __restrict__ Kb,
                                              unsigned short* __restrict__ Vt,
                                              unsigned short* __restrict__ Xg) {
    __shared__ unsigned short As[128][64 + PAD];
    __shared__ unsigned short Bs[128][64 + PAD];
    int m0 = blockIdx.x * 128;
    int n0 = blockIdx.y * 128;
    int t = threadIdx.x;
    int wave = t >> 6, lane = t & 63;
    int wr = wave >> 1, wc = wave & 1;
    int lane15 = lane & 15, kg = lane >> 4;
    f32x4 acc[4][4] = {};
    for (int k0 = 0; k0 < DS_; k0 += 64) {
        __syncthreads();
        {
            int r = t >> 1, half = t & 1;
            const float4* src = (const float4*)(X + (long)(m0 + r) * DS_ + k0 + half * 32);
            unsigned short* dst = &As[r][half * 32];
            #pragma unroll
            for (int ii = 0; ii < 8; ++ii) {
                float4 v = src[ii];
                dst[ii * 4 + 0] = f2b(v.x); dst[ii * 4 + 1] = f2b(v.y);
                dst[ii * 4 + 2] = f2b(v.z); dst[ii * 4 + 3] = f2b(v.w);
            }
            const uint4* wsrc = (const uint4*)(Wt + (long)(n0 + r) * DS_ + k0 + half * 32);
            uint4* wdst = (uint4*)&Bs[r][half * 32];
            wdst[0] = wsrc[0]; wdst[1] = wsrc[1]; wdst[2] = wsrc[2]; wdst[3] = wsrc[3];
        }
        __syncthreads();
        #pragma unroll
        for (int ks = 0; ks < 2; ++ks) {
            bf16x8 a[4], bb[4];
            #pragma unroll
            for (int mf = 0; mf < 4; ++mf)
                a[mf] = *(const bf16x8*)&As[wr * 64 + mf * 16 + lane15][ks * 32 + kg * 8];
            #pragma unroll
            for (int nf = 0; nf < 4; ++nf)
                bb[nf] = *(const bf16x8*)&Bs[wc * 64 + nf * 16 + lane15][ks * 32 + kg * 8];
            #pragma unroll
            for (int mf = 0; mf < 4; ++mf)
                #pragma unroll
                for (int nf = 0; nf < 4; ++nf)
                    acc[mf][nf] = __builtin_amdgcn_mfma_f32_16x16x32_bf16(a[mf], bb[nf], acc[mf][nf], 0, 0, 0);
        }
    }
    int p = n0 >> 10;                 // which projection (q,k,v,g)
    int lgrp = lane >> 4;
    #pragma unroll
    for (int mf = 0; mf < 4; ++mf) {
        #pragma unroll
        for (int nf = 0; nf < 4; ++nf) {
            int col = n0 + wc * 64 + nf * 16 + lane15;
            int ch = col & 1023;
            int h = ch >> 6, dh = ch & 63;
            int row0 = m0 + wr * 64 + mf * 16 + lgrp * 4;
            if (p == 0 || p == 1) {
                unsigned short* base = (p == 0) ? Qb : Kb;
                float scl = (p == 0) ? 0.125f : 1.0f;
                #pragma unroll
                for (int r = 0; r < 4; ++r) {
                    int row = row0 + r;
                    int b = row >> 9, n = row & 511;
                    base[(((long)(b * 16 + h)) * 512 + n) * 64 + dh] = f2b(acc[mf][nf][r] * scl);
                }
            } else if (p == 2) {
                int b = row0 >> 9, n = row0 & 511;
                ushort4 v;
                v.x = f2b(acc[mf][nf][0]); v.y = f2b(acc[mf][nf][1]);
                v.z = f2b(acc[mf][nf][2]); v.w = f2b(acc[mf][nf][3]);
                *(ushort4*)&Vt[(((long)(b * 16 + h)) * 64 + dh) * 512 + n] = v;
            } else {
                #pragma unroll
                for (int r = 0; r < 4; ++r) {
                    int row = row0 + r;
                    Xg[(long)row * 1024 + ch] = f2b(acc[mf][nf][r]);
                }
            }
        }
    }
}

// ---------------- fused flash attention: S=Q@K^T+bias, softmax, P@V, gate ---
// grid (8 i-blocks, 32 bh), 256 threads (4 waves, wave w owns i-rows w*16..+16)
__global__ __launch_bounds__(256) void k_flash(const unsigned short* __restrict__ Qb,
                                               const unsigned short* __restrict__ Kb,
                                               const unsigned short* __restrict__ Vt,
                                               const unsigned short* __restrict__ biasP,
                                               const unsigned short* __restrict__ Xg,
                                               unsigned short* __restrict__ Og) {
    __shared__ unsigned short Kt[64][72];    // [j][dh]
    __shared__ unsigned short Vs[64][72];    // [dh][j]
    __shared__ unsigned short Bt[64][72];    // [i][j] bias tile
    __shared__ unsigned short Ps[4][16][72]; // per-wave P [i][j]
    int bh = blockIdx.y;
    int b = bh >> 4, h = bh & 15;
    int i0 = blockIdx.x * 64;
    int t = threadIdx.x, w = t >> 6, lane = t & 63;
    int lane15 = lane & 15, lgrp = lane >> 4;

    // Q fragments (B-operand), row i = i0 + w*16 + lane15, pre-scaled by 0.125
    bf16x8 qf[2];
    #pragma unroll
    for (int kk = 0; kk < 2; ++kk)
        qf[kk] = *(const bf16x8*)&Qb[((long)bh * 512 + i0 + w * 16 + lane15) * 64 + kk * 32 + lgrp * 8];

    float m_run = -1e30f, l_run = 0.f;
    f32x4 o[4] = {};   // o[nf][r] = O[i0+w*16+lgrp*4+r][nf*16+lane15]

    for (int jt = 0; jt < 8; ++jt) {
        int j0 = jt * 64;
        __syncthreads();   // previous tile fully consumed
        #pragma unroll
        for (int i = 0; i < 2; ++i) {
            int f = i * 256 + t;
            int r = f >> 3, c = f & 7;
            *(uint4*)&Kt[r][c * 8] = *(const uint4*)&Kb[((long)bh * 512 + j0 + r) * 64 + c * 8];
            *(uint4*)&Vs[r][c * 8] = *(const uint4*)&Vt[((long)bh * 64 + r) * 512 + j0 + c * 8];
            *(uint4*)&Bt[r][c * 8] = *(const uint4*)&biasP[(((long)bh * 512) + i0 + r) * 512 + j0 + c * 8];
        }
        __syncthreads();

        // S^T[j][i]: A = K[j][dh], B = Q[i][dh]  ->  lane holds col i=lane15, rows j
        f32x4 s[4];
        #pragma unroll
        for (int nf = 0; nf < 4; ++nf) {
            f32x4 z = {};
            #pragma unroll
            for (int kk = 0; kk < 2; ++kk) {
                bf16x8 af = *(const bf16x8*)&Kt[nf * 16 + lane15][kk * 32 + lgrp * 8];
                z = __builtin_amdgcn_mfma_f32_16x16x32_bf16(af, qf[kk], z, 0, 0, 0);
            }
            s[nf] = z;
        }
        // add bias: s[nf][r] is S[i = i0 + w*16 + lane15][j = j0 + nf*16 + lgrp*4 + r]
        #pragma unroll
        for (int nf = 0; nf < 4; ++nf)
            #pragma unroll
            for (int r = 0; r < 4; ++r)
                s[nf][r] += b2f(Bt[w * 16 + lane15][nf * 16 + lgrp * 4 + r]);

        // online softmax, lane owns row i (16 j-values per lane); reduce across
        // the 4 lanes sharing lane15 (xor 16, 32)
        float pmax = s[0][0];
        #pragma unroll
        for (int nf = 0; nf < 4; ++nf)
            #pragma unroll
            for (int r = 0; r < 4; ++r) pmax = fmaxf(pmax, s[nf][r]);
        pmax = fmaxf(pmax, __shfl_xor(pmax, 16));
        pmax = fmaxf(pmax, __shfl_xor(pmax, 32));
        float m_new = fmaxf(m_run, pmax);
        float scale = __expf(m_run - m_new);
        float psum = 0.f;
        #pragma unroll
        for (int nf = 0; nf < 4; ++nf)
            #pragma unroll
            for (int r = 0; r < 4; ++r) {
                s[nf][r] = __expf(s[nf][r] - m_new);
                psum += s[nf][r];
            }
        psum += __shfl_xor(psum, 16);
        psum += __shfl_xor(psum, 32);
        l_run = l_run * scale + psum;
        m_run = m_new;
        // rescale O (o's rows are i = lgrp*4 + r; fetch that row's scale)
        #pragma unroll
        for (int r = 0; r < 4; ++r) {
            float sc = __shfl(scale, lgrp * 4 + r);
            #pragma unroll
            for (int nf = 0; nf < 4; ++nf) o[nf][r] *= sc;
        }
        // P -> LDS (bf16), wave-private
        #pragma unroll
        for (int nf = 0; nf < 4; ++nf)
            #pragma unroll
            for (int r = 0; r < 4; ++r)
                Ps[w][lane15][nf * 16 + lgrp * 4 + r] = f2b(s[nf][r]);
        // PV: A = P[i][j] (row=lane15), B = V[dh][j] (row=lane15 of Vs)
        #pragma unroll
        for (int kk = 0; kk < 2; ++kk) {
            bf16x8 pa = *(const bf16x8*)&Ps[w][lane15][kk * 32 + lgrp * 8];
            #pragma unroll
            for (int nf = 0; nf < 4; ++nf) {
                bf16x8 vb = *(const bf16x8*)&Vs[nf * 16 + lane15][kk * 32 + lgrp * 8];
                o[nf] = __builtin_amdgcn_mfma_f32_16x16x32_bf16(pa, vb, o[nf], 0, 0, 0);
            }
        }
    }
    // epilogue: divide by l, sigmoid gate, store
    #pragma unroll
    for (int r = 0; r < 4; ++r) {
        float l_r = __shfl(l_run, lgrp * 4 + r);
        float inv = 1.f / l_r;
        long grow = (long)b * 512 + i0 + w * 16 + lgrp * 4 + r;
        #pragma unroll
        for (int nf = 0; nf < 4; ++nf) {
            int dh = nf * 16 + lane15;
            float xgv = b2f(Xg[grow * 1024 + h * 64 + dh]);
            float gate = 1.f / (1.f + __expf(-xgv));
            Og[grow * 1024 + h * 64 + dh] = f2b(o[nf][r] * inv * gate);
        }
    }
}

// ---------------- output GEMM: out = Og @ w_o (M=1024,N=384,K=1024) ---------
__global__ __launch_bounds__(256) void k_out(const unsigned short* __restrict__ Og,
                                             const unsigned short* __restrict__ Wot,
                                             float* __restrict__ out) {
    __shared__ unsigned short As[128][64 + PAD];
    __shared__ unsigned short Bs[128][64 + PAD];
    int m0 = blockIdx.x * 128, n0 = blockIdx.y * 128;
    int t = threadIdx.x, wave = t >> 6, lane = t & 63;
    int wr = wave >> 1, wc = wave & 1;
    int lane15 = lane & 15, kg = lane >> 4;
    f32x4 acc[4][4] = {};
    for (int k0 = 0; k0 < 1024; k0 += 64) {
        __syncthreads();
        {
            int r = t >> 1, half = t & 1;
            const uint4* src = (const uint4*)(Og + (long)(m0 + r) * 1024 + k0 + half * 32);
            uint4* dst = (uint4*)&As[r][half * 32];
            dst[0] = src[0]; dst[1] = src[1]; dst[2] = src[2]; dst[3] = src[3];
            const uint4* wsrc = (const uint4*)(Wot + (long)(n0 + r) * 1024 + k0 + half * 32);
            uint4* wdst = (uint4*)&Bs[r][half * 32];
            wdst[0] = wsrc[0]; wdst[1] = wsrc[1]; wdst[2] = wsrc[2]; wdst[3] = wsrc[3];
        }
        __syncthreads();
        #pragma unroll
        for (int ks = 0; ks < 2; ++ks) {
            bf16x8 a[4], bb[4];
            #pragma unroll
            for (int mf = 0; mf < 4; ++mf)
                a[mf] = *(const bf16x8*)&As[wr * 64 + mf * 16 + lane15][ks * 32 + kg * 8];
            #pragma unroll
            for (int nf = 0; nf < 4; ++nf)
                bb[nf] = *(const bf16x8*)&Bs[wc * 64 + nf * 16 + lane15][ks * 32 + kg * 8];
            #pragma unroll
            for (int mf = 0; mf < 4; ++mf)
                #pragma unroll
                for (int nf = 0; nf < 4; ++nf)
                    acc[mf][nf] = __builtin_amdgcn_mfma_f32_16x16x32_bf16(a[mf], bb[nf], acc[mf][nf], 0, 0, 0);
        }
    }
    int lgrp = lane >> 4;
    #pragma unroll
    for (int mf = 0; mf < 4; ++mf) {
        #pragma unroll
        for (int nf = 0; nf < 4; ++nf) {
            int col = n0 + wc * 64 + nf * 16 + lane15;
            int row0 = m0 + wr * 64 + mf * 16 + lgrp * 4;
            #pragma unroll
            for (int r = 0; r < 4; ++r)
                out[(long)(row0 + r) * DS_ + col] = acc[mf][nf][r];
        }
    }
}

extern "C" void kernel_launch(void* const* d_in, const int* in_sizes, int n_in,
                              void* d_out, int out_size, void* d_ws, size_t ws_size,
                              hipStream_t stream) {
    const float* single = (const float*)d_in[0];
    const float* pw     = (const float*)d_in[1];
    const float* gamma  = (const float*)d_in[2];
    const float* beta   = (const float*)d_in[3];
    const float* wb     = (const float*)d_in[4];
    const float* abb    = (const float*)d_in[5];
    const float* wq     = (const float*)d_in[6];
    const float* wk     = (const float*)d_in[7];
    const float* wv     = (const float*)d_in[8];
    const float* wg     = (const float*)d_in[9];
    const float* wo     = (const float*)d_in[10];
    float* out = (float*)d_out;
    char* ws = (char*)d_ws;

    unsigned short* SP  = (unsigned short*)(ws);                 // 16 MB bias [b][h][i][j]
    unsigned short* Qb  = (unsigned short*)(ws + 16777216);      // 2 MB (pre-scaled 0.125)
    unsigned short* Kb  = (unsigned short*)(ws + 18874368);      // 2 MB
    unsigned short* Vt  = (unsigned short*)(ws + 20971520);      // 2 MB [b][h][dh][n]
    unsigned short* Xg  = (unsigned short*)(ws + 23068672);      // 2 MB
    unsigned short* Og  = (unsigned short*)(ws + 25165824);      // 2 MB
    unsigned short* Wt  = (unsigned short*)(ws + 27262976);      // 3 MB [4*1024][384]
    unsigned short* Wot = (unsigned short*)(ws + 30408704);      // 0.75 MB [384][1024]

    k_transpose_all<<<dim3(32, 32, 5), 256, 0, stream>>>(wq, wk, wv, wg, wo, Wt, Wot);
    k_bias<<<2048, 256, 0, stream>>>(pw, gamma, beta, wb, abb, SP);
    k_proj<<<dim3(8, 32), 256, 0, stream>>>(single, Wt, Qb, Kb, Vt, Xg);
    k_flash<<<dim3(8, 32), 256, 0, stream>>>(Qb, Kb, Vt, SP, Xg, Og);
    k_out<<<dim3(8, 3), 256, 0, stream>>>(Og, Wot, out);
}